// Round 1
// baseline (954.410 us; speedup 1.0000x reference)
//
#include <hip/hip_runtime.h>

#define NEPS 1e-5f

// ---------------- CSR build ----------------
__global__ void k_deg(const int* __restrict__ ei, int* __restrict__ deg_cnt, int E_) {
  int i = blockIdx.x * blockDim.x + threadIdx.x;
  int stride = gridDim.x * blockDim.x;
  for (int e = i; e < E_; e += stride) atomicAdd(&deg_cnt[ei[E_ + e]], 1);
}

__global__ void k_scan(const int* __restrict__ cnt, int* __restrict__ row_ptr, int N_) {
  __shared__ int wsum[16];
  __shared__ int carry;
  int t = threadIdx.x;
  int lane = t & 63, w = t >> 6;
  if (t == 0) { carry = 0; row_ptr[0] = 0; }
  __syncthreads();
  for (int base = 0; base < N_; base += 1024) {
    int i = base + t;
    int v = (i < N_) ? cnt[i] : 0;
    int sv = v;
    #pragma unroll
    for (int off = 1; off < 64; off <<= 1) {
      int u = __shfl_up(sv, off);
      if (lane >= off) sv += u;
    }
    if (lane == 63) wsum[w] = sv;
    __syncthreads();
    if (w == 0 && lane < 16) {
      int sw = wsum[lane];
      #pragma unroll
      for (int off = 1; off < 16; off <<= 1) {
        int u = __shfl_up(sw, off);
        if (lane >= off) sw += u;
      }
      wsum[lane] = sw;
    }
    __syncthreads();
    int blockoff = carry + (w ? wsum[w - 1] : 0);
    if (i < N_) row_ptr[i + 1] = blockoff + sv;
    __syncthreads();
    if (t == 1023) carry += wsum[15];
    __syncthreads();
  }
}

__global__ void k_node(const int* __restrict__ deg_cnt, float* __restrict__ dis,
                       float* __restrict__ di, int N_) {
  int i = blockIdx.x * blockDim.x + threadIdx.x;
  int stride = gridDim.x * blockDim.x;
  for (int n = i; n < N_; n += stride) {
    float dg = (float)deg_cnt[n] + 1.0f;
    dis[n] = rsqrtf(dg);
    di[n] = 1.0f / dg;
  }
}

__global__ void k_scatter(const int* __restrict__ ei, const int* __restrict__ row_ptr,
                          int* __restrict__ cursor, int* __restrict__ csr, int E_) {
  int i = blockIdx.x * blockDim.x + threadIdx.x;
  int stride = gridDim.x * blockDim.x;
  for (int e = i; e < E_; e += stride) {
    int s_ = ei[e], d_ = ei[E_ + e];
    int slot = atomicAdd(&cursor[d_], 1);
    csr[row_ptr[d_] + slot] = s_;
  }
}

// ---------------- BN0 stats on x ----------------
__global__ void k_xstats(const float* __restrict__ x, float* __restrict__ stats, int N_) {
  float s1[3] = {0, 0, 0}, s2[3] = {0, 0, 0};
  int i = blockIdx.x * blockDim.x + threadIdx.x;
  int stride = gridDim.x * blockDim.x;
  for (int n = i; n < N_; n += stride) {
    #pragma unroll
    for (int c = 0; c < 3; c++) { float v = x[n * 3 + c]; s1[c] += v; s2[c] += v * v; }
  }
  #pragma unroll
  for (int c = 0; c < 3; c++) {
    for (int off = 32; off > 0; off >>= 1) {
      s1[c] += __shfl_down(s1[c], off);
      s2[c] += __shfl_down(s2[c], off);
    }
  }
  if ((threadIdx.x & 63) == 0) {
    #pragma unroll
    for (int c = 0; c < 3; c++) { atomicAdd(&stats[c], s1[c]); atomicAdd(&stats[4 + c], s2[c]); }
  }
}

// fold BN0 into W1:  h0 = a*x + d  ->  W1a[c][j] = a[c]*W1[c][j],  u1[j] = d @ W1
__global__ void k_prep0(const float* __restrict__ stats, const float* __restrict__ g0,
                        const float* __restrict__ b0, const float* __restrict__ W1,
                        float* __restrict__ W1a, float* __restrict__ u1, int N_) {
  __shared__ float a[3], dd[3];
  int t = threadIdx.x;
  if (t < 3) {
    float m = stats[t] / N_;
    float v = stats[4 + t] / N_ - m * m;
    float sc = g0[t] * rsqrtf(v + NEPS);
    a[t] = sc; dd[t] = b0[t] - m * sc;
  }
  __syncthreads();
  if (t < 128) {
    float u = 0.f;
    #pragma unroll
    for (int c = 0; c < 3; c++) {
      float w = W1[c * 128 + t];
      W1a[c * 128 + t] = a[c] * w;
      u = fmaf(dd[c], w, u);
    }
    u1[t] = u;
  }
}

// ---------------- layer-1: aggregate 3-dim x first ----------------
__global__ void k_gather0(const float* __restrict__ x, const int* __restrict__ csr,
                          const int* __restrict__ row_ptr, const float* __restrict__ dis,
                          const float* __restrict__ di, float4* __restrict__ aggx, int N_) {
  int i = blockIdx.x * blockDim.x + threadIdx.x;
  int stride = gridDim.x * blockDim.x;
  for (int n = i; n < N_; n += stride) {
    int st = row_ptr[n], en = row_ptr[n + 1];
    float a0 = 0, a1 = 0, a2 = 0, sd = 0;
    for (int e = st; e < en; e++) {
      int s_ = csr[e];
      float w = dis[s_];
      a0 = fmaf(w, x[s_ * 3 + 0], a0);
      a1 = fmaf(w, x[s_ * 3 + 1], a1);
      a2 = fmaf(w, x[s_ * 3 + 2], a2);
      sd += w;
    }
    float dn = dis[n], dl = di[n];
    float4 o;
    o.x = dn * a0 + dl * x[n * 3 + 0];
    o.y = dn * a1 + dl * x[n * 3 + 1];
    o.z = dn * a2 + dl * x[n * 3 + 2];
    o.w = dn * sd + dl;              // s[n] multiplies the BN-shift column u1
    aggx[n] = o;
  }
}

// y1 = relu(aggx @ W1a + s*u1 + b1)
__global__ void k_gemm1(const float4* __restrict__ aggx, const float* __restrict__ W1a,
                        const float* __restrict__ u1, const float* __restrict__ b1,
                        float* __restrict__ y, int N_) {
  int i = blockIdx.x * blockDim.x + threadIdx.x;
  int stride = gridDim.x * blockDim.x;
  int total = N_ * 32;
  for (int idx = i; idx < total; idx += stride) {
    int n = idx >> 5, q = (idx & 31) * 4;
    float4 A = aggx[n];
    float4 w0 = *(const float4*)&W1a[q];
    float4 w1 = *(const float4*)&W1a[128 + q];
    float4 w2 = *(const float4*)&W1a[256 + q];
    float4 uu = *(const float4*)&u1[q];
    float4 bb = *(const float4*)&b1[q];
    float4 o;
    o.x = fmaxf(fmaf(A.x, w0.x, fmaf(A.y, w1.x, fmaf(A.z, w2.x, fmaf(A.w, uu.x, bb.x)))), 0.f);
    o.y = fmaxf(fmaf(A.x, w0.y, fmaf(A.y, w1.y, fmaf(A.z, w2.y, fmaf(A.w, uu.y, bb.y)))), 0.f);
    o.z = fmaxf(fmaf(A.x, w0.z, fmaf(A.y, w1.z, fmaf(A.z, w2.z, fmaf(A.w, uu.z, bb.z)))), 0.f);
    o.w = fmaxf(fmaf(A.x, w0.w, fmaf(A.y, w1.w, fmaf(A.z, w2.w, fmaf(A.w, uu.w, bb.w)))), 0.f);
    *(float4*)&y[n * 128 + q] = o;
  }
}

// ---------------- per-channel stats of an [N,128] activation ----------------
__global__ void k_stats(const float* __restrict__ y, float* __restrict__ S1,
                        float* __restrict__ S2, int N_) {
  int c = threadIdx.x;  // 128 threads
  float s1 = 0, s2 = 0;
  for (int n = blockIdx.x; n < N_; n += gridDim.x) {
    float v = y[n * 128 + c];
    s1 += v; s2 += v * v;
  }
  atomicAdd(&S1[c], s1);
  atomicAdd(&S2[c], s2);
}

// fold BN(prev) into W:  Wp[k][j] = scale[k]*W[k][j],  cb[j] = shift @ W
__global__ void k_prepW(const float* __restrict__ S1, const float* __restrict__ S2,
                        const float* __restrict__ g_, const float* __restrict__ b_,
                        const float* __restrict__ W, float* __restrict__ Wp,
                        float* __restrict__ cb, int N_) {
  __shared__ float sc[128], sh[128];
  int t = threadIdx.x;
  if (t < 128) {
    float m = S1[t] / N_;
    float v = S2[t] / N_ - m * m;
    float s = g_[t] * rsqrtf(v + NEPS);
    sc[t] = s; sh[t] = b_[t] - m * s;
  }
  __syncthreads();
  for (int idx = t; idx < 128 * 128; idx += blockDim.x) Wp[idx] = sc[idx >> 7] * W[idx];
  for (int j = t; j < 128; j += blockDim.x) {
    float acc = 0;
    for (int k = 0; k < 128; k++) acc = fmaf(sh[k], W[k * 128 + j], acc);
    cb[j] = acc;
  }
}

// hw = y @ Wp + cb   (64-node tile per block, Wp from L2, y tile in LDS)
__global__ __launch_bounds__(256) void k_gemm(const float* __restrict__ y,
                                              const float* __restrict__ Wp,
                                              const float* __restrict__ cb,
                                              float* __restrict__ hw, int N_) {
  __shared__ float yl[64][128];
  int t = threadIdx.x;
  int base = blockIdx.x * 64;
  for (int i = t; i < 64 * 32; i += 256) {
    int r = i >> 5;
    int cq = (i & 31) * 4;
    int n = base + r;
    float4 v = (n < N_) ? *(const float4*)&y[n * 128 + cq] : float4{0, 0, 0, 0};
    *(float4*)&yl[r][cq] = v;
  }
  __syncthreads();
  int tn = t >> 5, tj = t & 31;
  float4 acc[8];
  float4 cbv = *(const float4*)&cb[tj * 4];
  #pragma unroll
  for (int r = 0; r < 8; r++) acc[r] = cbv;
  for (int kk = 0; kk < 128; kk++) {
    float4 w = *(const float4*)&Wp[kk * 128 + tj * 4];
    #pragma unroll
    for (int r = 0; r < 8; r++) {
      float yv = yl[tn * 8 + r][kk];
      acc[r].x = fmaf(yv, w.x, acc[r].x);
      acc[r].y = fmaf(yv, w.y, acc[r].y);
      acc[r].z = fmaf(yv, w.z, acc[r].z);
      acc[r].w = fmaf(yv, w.w, acc[r].w);
    }
  }
  #pragma unroll
  for (int r = 0; r < 8; r++) {
    int n = base + tn * 8 + r;
    if (n < N_) *(float4*)&hw[n * 128 + tj * 4] = acc[r];
  }
}

// y_out = relu(dis[n]*sum_src dis[src]*hw[src] + di[n]*hw[n] + b)   one wave per node
__global__ void k_gather(const float* __restrict__ hw, const int* __restrict__ csr,
                         const int* __restrict__ row_ptr, const float* __restrict__ dis,
                         const float* __restrict__ di, const float* __restrict__ bL,
                         float* __restrict__ y, int N_) {
  int wid = (blockIdx.x * blockDim.x + threadIdx.x) >> 6;
  int lane = threadIdx.x & 63;
  int nw = (gridDim.x * blockDim.x) >> 6;
  for (int n = wid; n < N_; n += nw) {
    int st = row_ptr[n], en = row_ptr[n + 1];
    float ax = 0.f, ay = 0.f;
    for (int e = st; e < en; e++) {
      int s_ = csr[e];
      float w = dis[s_];
      float2 v = *(const float2*)&hw[s_ * 128 + lane * 2];
      ax = fmaf(w, v.x, ax);
      ay = fmaf(w, v.y, ay);
    }
    float dn = dis[n], dl = di[n];
    float2 hv = *(const float2*)&hw[n * 128 + lane * 2];
    float2 bb = *(const float2*)&bL[lane * 2];
    float2 o;
    o.x = fmaxf(fmaf(ax, dn, fmaf(hv.x, dl, bb.x)), 0.f);
    o.y = fmaxf(fmaf(ay, dn, fmaf(hv.y, dl, bb.y)), 0.f);
    *(float2*)&y[n * 128 + lane * 2] = o;
  }
}

// ---------------- pooling + classifier ----------------
__device__ inline int lb_dev(const int* b, int n, int v) {
  int lo = 0, hi = n;
  while (lo < hi) { int mid = (lo + hi) >> 1; if (b[mid] < v) lo = mid + 1; else hi = mid; }
  return lo;
}

__global__ void k_pool(const float* __restrict__ y, const int* __restrict__ batch,
                       float* __restrict__ pooled, float* __restrict__ cntf, int N_, int G_) {
  int g = blockIdx.x, c = threadIdx.x;  // 128 threads
  __shared__ int s_lo, s_hi;
  if (c == 0) { s_lo = lb_dev(batch, N_, g); s_hi = lb_dev(batch, N_, g + 1); }
  __syncthreads();
  float acc = 0;
  for (int n = s_lo; n < s_hi; n++) acc += y[n * 128 + c];
  pooled[g * 128 + c] = acc;
  if (c == 0) cntf[g] = (float)(s_hi - s_lo);
}

// fold BN3 into classifier:  Wc1p[k][j] = sc[k]*Wc1[k][j], bc1p = bc1 + sh @ Wc1
__global__ void k_prepC(const float* __restrict__ S1, const float* __restrict__ S2,
                        const float* __restrict__ g_, const float* __restrict__ b_,
                        const float* __restrict__ Wc1, const float* __restrict__ bc1,
                        float* __restrict__ Wc1p, float* __restrict__ bc1p, int N_) {
  __shared__ float sc[128], sh[128];
  int t = threadIdx.x;  // 128
  {
    float m = S1[t] / N_;
    float v = S2[t] / N_ - m * m;
    float s = g_[t] * rsqrtf(v + NEPS);
    sc[t] = s; sh[t] = b_[t] - m * s;
  }
  __syncthreads();
  for (int idx = t; idx < 128 * 64; idx += 128) Wc1p[idx] = sc[idx >> 6] * Wc1[idx];
  if (t < 64) {
    float acc = bc1[t];
    for (int k = 0; k < 128; k++) acc = fmaf(sh[k], Wc1[k * 64 + t], acc);
    bc1p[t] = acc;
  }
}

__global__ void k_cls(const float* __restrict__ pooled, const float* __restrict__ cntf,
                      const float* __restrict__ Wc1p, const float* __restrict__ bc1p,
                      const float* __restrict__ Wc2, const float* __restrict__ bc2,
                      float* __restrict__ out, int G_) {
  __shared__ float p[128];
  __shared__ float z[64];
  int g = blockIdx.x, t = threadIdx.x;  // 64 threads
  float inv = 1.f / fmaxf(cntf[g], 1.f);
  p[t] = pooled[g * 128 + t] * inv;
  p[t + 64] = pooled[g * 128 + 64 + t] * inv;
  __syncthreads();
  float acc = bc1p[t];
  for (int k = 0; k < 128; k++) acc = fmaf(p[k], Wc1p[k * 64 + t], acc);
  z[t] = fmaxf(acc, 0.f);
  __syncthreads();
  if (t < 2) {
    float o = bc2[t];
    for (int j = 0; j < 64; j++) o = fmaf(z[j], Wc2[j * 2 + t], o);
    out[g * 2 + t] = o;
  }
}

extern "C" void kernel_launch(void* const* d_in, const int* in_sizes, int n_in,
                              void* d_out, int out_size, void* d_ws, size_t ws_size,
                              hipStream_t stream) {
  const float* x    = (const float*)d_in[0];
  const int*   ei   = (const int*)d_in[1];
  const int*   batch= (const int*)d_in[2];
  const float* W1   = (const float*)d_in[3];
  const float* b1   = (const float*)d_in[4];
  const float* W2   = (const float*)d_in[5];
  const float* b2   = (const float*)d_in[6];
  const float* W3   = (const float*)d_in[7];
  const float* b3   = (const float*)d_in[8];
  const float* bn0g = (const float*)d_in[9];
  const float* bn0b = (const float*)d_in[10];
  const float* bn1g = (const float*)d_in[11];
  const float* bn1b = (const float*)d_in[12];
  const float* bn2g = (const float*)d_in[13];
  const float* bn2b = (const float*)d_in[14];
  const float* bn3g = (const float*)d_in[15];
  const float* bn3b = (const float*)d_in[16];
  const float* Wc1  = (const float*)d_in[17];
  const float* bc1  = (const float*)d_in[18];
  const float* Wc2  = (const float*)d_in[19];
  const float* bc2  = (const float*)d_in[20];

  const int N_ = in_sizes[2];
  const int E_ = in_sizes[1] / 2;
  const int G_ = out_size / 2;

  char* ws = (char*)d_ws;
  size_t off = 0;
  auto A = [&](size_t bytes) { size_t o = off; off = (off + bytes + 255) & ~(size_t)255; return o; };
  size_t o_deg   = A((size_t)N_ * 4);
  size_t o_cur   = A((size_t)N_ * 4);
  size_t o_stats = A(1024 * 4);
  size_t zero_end = off;
  size_t o_rowp  = A((size_t)(N_ + 1) * 4);
  size_t o_csr   = A((size_t)E_ * 4);
  size_t o_dis   = A((size_t)N_ * 4);
  size_t o_di    = A((size_t)N_ * 4);
  size_t o_aggx  = A((size_t)N_ * 16);
  size_t o_W1a   = A(384 * 4);
  size_t o_u1    = A(128 * 4);
  size_t o_Wp    = A(16384 * 4);
  size_t o_cb    = A(128 * 4);
  size_t o_Wc1p  = A(8192 * 4);
  size_t o_bc1p  = A(64 * 4);
  size_t o_pool  = A((size_t)G_ * 128 * 4);
  size_t o_cnt   = A((size_t)G_ * 4);
  size_t o_bufA  = A((size_t)N_ * 128 * 4);
  size_t o_bufB  = A((size_t)N_ * 128 * 4);
  (void)ws_size; (void)n_in;

  int*   deg_cnt = (int*)(ws + o_deg);
  int*   cursor  = (int*)(ws + o_cur);
  float* stats   = (float*)(ws + o_stats);
  int*   row_ptr = (int*)(ws + o_rowp);
  int*   csr     = (int*)(ws + o_csr);
  float* dis     = (float*)(ws + o_dis);
  float* di      = (float*)(ws + o_di);
  float4* aggx   = (float4*)(ws + o_aggx);
  float* W1a     = (float*)(ws + o_W1a);
  float* u1      = (float*)(ws + o_u1);
  float* Wp      = (float*)(ws + o_Wp);
  float* cb      = (float*)(ws + o_cb);
  float* Wc1p    = (float*)(ws + o_Wc1p);
  float* bc1p    = (float*)(ws + o_bc1p);
  float* pooled  = (float*)(ws + o_pool);
  float* cntf    = (float*)(ws + o_cnt);
  float* bufA    = (float*)(ws + o_bufA);
  float* bufB    = (float*)(ws + o_bufB);

  hipMemsetAsync(ws, 0, zero_end, stream);

  int nb_nodes = (N_ + 255) / 256;
  int nb_edges = 4096;

  k_deg<<<nb_edges, 256, 0, stream>>>(ei, deg_cnt, E_);
  k_xstats<<<256, 256, 0, stream>>>(x, stats, N_);
  k_scan<<<1, 1024, 0, stream>>>(deg_cnt, row_ptr, N_);
  k_node<<<nb_nodes, 256, 0, stream>>>(deg_cnt, dis, di, N_);
  k_scatter<<<nb_edges, 256, 0, stream>>>(ei, row_ptr, cursor, csr, E_);
  k_prep0<<<1, 128, 0, stream>>>(stats, bn0g, bn0b, W1, W1a, u1, N_);
  k_gather0<<<nb_nodes, 256, 0, stream>>>(x, csr, row_ptr, dis, di, aggx, N_);
  k_gemm1<<<(N_ * 32 + 255) / 256, 256, 0, stream>>>(aggx, W1a, u1, b1, bufB, N_);

  // layer 2
  k_stats<<<256, 128, 0, stream>>>(bufB, stats + 128, stats + 256, N_);
  k_prepW<<<1, 256, 0, stream>>>(stats + 128, stats + 256, bn1g, bn1b, W2, Wp, cb, N_);
  k_gemm<<<(N_ + 63) / 64, 256, 0, stream>>>(bufB, Wp, cb, bufA, N_);
  k_gather<<<(N_ + 3) / 4, 256, 0, stream>>>(bufA, csr, row_ptr, dis, di, b2, bufB, N_);

  // layer 3
  k_stats<<<256, 128, 0, stream>>>(bufB, stats + 384, stats + 512, N_);
  k_prepW<<<1, 256, 0, stream>>>(stats + 384, stats + 512, bn2g, bn2b, W3, Wp, cb, N_);
  k_gemm<<<(N_ + 63) / 64, 256, 0, stream>>>(bufB, Wp, cb, bufA, N_);
  k_gather<<<(N_ + 3) / 4, 256, 0, stream>>>(bufA, csr, row_ptr, dis, di, b3, bufB, N_);

  // BN3 stats + pool + classifier
  k_stats<<<256, 128, 0, stream>>>(bufB, stats + 640, stats + 768, N_);
  k_pool<<<G_, 128, 0, stream>>>(bufB, batch, pooled, cntf, N_, G_);
  k_prepC<<<1, 128, 0, stream>>>(stats + 640, stats + 768, bn3g, bn3b, Wc1, bc1, Wc1p, bc1p, N_);
  k_cls<<<G_, 64, 0, stream>>>(pooled, cntf, Wc1p, bc1p, Wc2, bc2, (float*)d_out, G_);
}

// Round 2
// 922.950 us; speedup vs baseline: 1.0341x; 1.0341x over previous
//
#include <hip/hip_runtime.h>

#define NEPS 1e-5f

// pack two f32 -> two bf16 (RNE) in one uint: low16 = a, high16 = b
__device__ inline unsigned int bfpack(float a, float b) {
  unsigned int ua = __float_as_uint(a), ub = __float_as_uint(b);
  ua += 0x7fff + ((ua >> 16) & 1);
  ub += 0x7fff + ((ub >> 16) & 1);
  return (ua >> 16) | (ub & 0xffff0000u);
}

// ---------------- CSR build ----------------
__global__ void k_deg(const int* __restrict__ ei, int* __restrict__ deg_cnt, int E_) {
  int i = blockIdx.x * blockDim.x + threadIdx.x;
  int stride = gridDim.x * blockDim.x;
  for (int e = i; e < E_; e += stride) atomicAdd(&deg_cnt[ei[E_ + e]], 1);
}

// block-local inclusive scan of deg_cnt into row_ptr[i+1]; block sums to bsum
__global__ __launch_bounds__(256) void k_scanA(const int* __restrict__ cnt, int* __restrict__ rp1,
                                               int* __restrict__ bsum, int N_) {
  int b = blockIdx.x, t = threadIdx.x;
  int i = b * 256 + t;
  int lane = t & 63, w = t >> 6;
  int sv = (i < N_) ? cnt[i] : 0;
  #pragma unroll
  for (int off = 1; off < 64; off <<= 1) {
    int u = __shfl_up(sv, off);
    if (lane >= off) sv += u;
  }
  __shared__ int wsum[4];
  if (lane == 63) wsum[w] = sv;
  __syncthreads();
  int add = 0;
  for (int k = 0; k < w; k++) add += wsum[k];
  sv += add;
  if (i < N_) rp1[i] = sv;  // rp1 = row_ptr + 1
  if (t == 255) bsum[b] = sv;
}

// single-block inclusive scan of block sums (NB <= 256)
__global__ __launch_bounds__(256) void k_scanB(int* __restrict__ bsum, int NB) {
  int t = threadIdx.x;
  int lane = t & 63, w = t >> 6;
  int sv = (t < NB) ? bsum[t] : 0;
  #pragma unroll
  for (int off = 1; off < 64; off <<= 1) {
    int u = __shfl_up(sv, off);
    if (lane >= off) sv += u;
  }
  __shared__ int wsum[4];
  if (lane == 63) wsum[w] = sv;
  __syncthreads();
  int add = 0;
  for (int k = 0; k < w; k++) add += wsum[k];
  sv += add;
  if (t < NB) bsum[t] = sv;
}

// add block offsets; also compute dis/di and pack xp = {x0,x1,x2,dis}
__global__ __launch_bounds__(256) void k_scanC(int* __restrict__ row_ptr, const int* __restrict__ bsum,
                                               const int* __restrict__ deg_cnt, const float* __restrict__ x,
                                               float* __restrict__ dis, float* __restrict__ di,
                                               float4* __restrict__ xp, int N_) {
  int b = blockIdx.x;
  int i = b * 256 + threadIdx.x;
  if (i == 0) row_ptr[0] = 0;
  if (i >= N_) return;
  int base = b ? bsum[b - 1] : 0;
  row_ptr[i + 1] += base;
  float dg = (float)deg_cnt[i] + 1.0f;
  float ds_ = rsqrtf(dg);
  dis[i] = ds_;
  di[i] = 1.0f / dg;
  float4 v;
  v.x = x[i * 3 + 0]; v.y = x[i * 3 + 1]; v.z = x[i * 3 + 2]; v.w = ds_;
  xp[i] = v;
}

__global__ void k_scatter(const int* __restrict__ ei, const int* __restrict__ row_ptr,
                          int* __restrict__ cursor, int* __restrict__ csr, int E_) {
  int i = blockIdx.x * blockDim.x + threadIdx.x;
  int stride = gridDim.x * blockDim.x;
  for (int e = i; e < E_; e += stride) {
    int s_ = ei[e], d_ = ei[E_ + e];
    int slot = atomicAdd(&cursor[d_], 1);
    csr[row_ptr[d_] + slot] = s_;
  }
}

// ---------------- BN0 stats on x ----------------
__global__ void k_xstats(const float* __restrict__ x, float* __restrict__ stats, int N_) {
  float s1[3] = {0, 0, 0}, s2[3] = {0, 0, 0};
  int i = blockIdx.x * blockDim.x + threadIdx.x;
  int stride = gridDim.x * blockDim.x;
  for (int n = i; n < N_; n += stride) {
    #pragma unroll
    for (int c = 0; c < 3; c++) { float v = x[n * 3 + c]; s1[c] += v; s2[c] += v * v; }
  }
  #pragma unroll
  for (int c = 0; c < 3; c++) {
    for (int off = 32; off > 0; off >>= 1) {
      s1[c] += __shfl_down(s1[c], off);
      s2[c] += __shfl_down(s2[c], off);
    }
  }
  if ((threadIdx.x & 63) == 0) {
    #pragma unroll
    for (int c = 0; c < 3; c++) { atomicAdd(&stats[c], s1[c]); atomicAdd(&stats[4 + c], s2[c]); }
  }
}

// fold BN0 into W1
__global__ void k_prep0(const float* __restrict__ stats, const float* __restrict__ g0,
                        const float* __restrict__ b0, const float* __restrict__ W1,
                        float* __restrict__ W1a, float* __restrict__ u1, int N_) {
  __shared__ float a[3], dd[3];
  int t = threadIdx.x;
  if (t < 3) {
    float m = stats[t] / N_;
    float v = stats[4 + t] / N_ - m * m;
    float sc = g0[t] * rsqrtf(v + NEPS);
    a[t] = sc; dd[t] = b0[t] - m * sc;
  }
  __syncthreads();
  if (t < 128) {
    float u = 0.f;
    #pragma unroll
    for (int c = 0; c < 3; c++) {
      float w = W1[c * 128 + t];
      W1a[c * 128 + t] = a[c] * w;
      u = fmaf(dd[c], w, u);
    }
    u1[t] = u;
  }
}

// ---------------- layer-1: aggregate 3-dim x first ----------------
__global__ void k_gather0(const float4* __restrict__ xp, const int* __restrict__ csr,
                          const int* __restrict__ row_ptr, const float* __restrict__ di,
                          float4* __restrict__ aggx, int N_) {
  int i = blockIdx.x * blockDim.x + threadIdx.x;
  int stride = gridDim.x * blockDim.x;
  for (int n = i; n < N_; n += stride) {
    int st = row_ptr[n], en = row_ptr[n + 1];
    float a0 = 0, a1 = 0, a2 = 0, sd = 0;
    for (int e = st; e < en; e++) {
      float4 v = xp[csr[e]];
      a0 = fmaf(v.w, v.x, a0);
      a1 = fmaf(v.w, v.y, a1);
      a2 = fmaf(v.w, v.z, a2);
      sd += v.w;
    }
    float4 xn = xp[n];
    float dn = xn.w, dl = di[n];
    float4 o;
    o.x = dn * a0 + dl * xn.x;
    o.y = dn * a1 + dl * xn.y;
    o.z = dn * a2 + dl * xn.z;
    o.w = dn * sd + dl;
    aggx[n] = o;
  }
}

// y1 = relu(aggx @ W1a + s*u1 + b1)
__global__ void k_gemm1(const float4* __restrict__ aggx, const float* __restrict__ W1a,
                        const float* __restrict__ u1, const float* __restrict__ b1,
                        float* __restrict__ y, int N_) {
  int i = blockIdx.x * blockDim.x + threadIdx.x;
  int stride = gridDim.x * blockDim.x;
  int total = N_ * 32;
  for (int idx = i; idx < total; idx += stride) {
    int n = idx >> 5, q = (idx & 31) * 4;
    float4 A = aggx[n];
    float4 w0 = *(const float4*)&W1a[q];
    float4 w1 = *(const float4*)&W1a[128 + q];
    float4 w2 = *(const float4*)&W1a[256 + q];
    float4 uu = *(const float4*)&u1[q];
    float4 bb = *(const float4*)&b1[q];
    float4 o;
    o.x = fmaxf(fmaf(A.x, w0.x, fmaf(A.y, w1.x, fmaf(A.z, w2.x, fmaf(A.w, uu.x, bb.x)))), 0.f);
    o.y = fmaxf(fmaf(A.x, w0.y, fmaf(A.y, w1.y, fmaf(A.z, w2.y, fmaf(A.w, uu.y, bb.y)))), 0.f);
    o.z = fmaxf(fmaf(A.x, w0.z, fmaf(A.y, w1.z, fmaf(A.z, w2.z, fmaf(A.w, uu.z, bb.z)))), 0.f);
    o.w = fmaxf(fmaf(A.x, w0.w, fmaf(A.y, w1.w, fmaf(A.z, w2.w, fmaf(A.w, uu.w, bb.w)))), 0.f);
    *(float4*)&y[n * 128 + q] = o;
  }
}

// per-channel stats of an [N,128] activation (layer-1 output only)
__global__ void k_stats(const float* __restrict__ y, float* __restrict__ S1,
                        float* __restrict__ S2, int N_) {
  int c = threadIdx.x;  // 128 threads
  float s1 = 0, s2 = 0;
  for (int n = blockIdx.x; n < N_; n += gridDim.x) {
    float v = y[n * 128 + c];
    s1 += v; s2 += v * v;
  }
  atomicAdd(&S1[c], s1);
  atomicAdd(&S2[c], s2);
}

// fold BN(prev) into W
__global__ void k_prepW(const float* __restrict__ S1, const float* __restrict__ S2,
                        const float* __restrict__ g_, const float* __restrict__ b_,
                        const float* __restrict__ W, float* __restrict__ Wp,
                        float* __restrict__ cb, int N_) {
  __shared__ float sc[128], sh[128];
  int t = threadIdx.x;
  if (t < 128) {
    float m = S1[t] / N_;
    float v = S2[t] / N_ - m * m;
    float s = g_[t] * rsqrtf(v + NEPS);
    sc[t] = s; sh[t] = b_[t] - m * s;
  }
  __syncthreads();
  for (int idx = t; idx < 128 * 128; idx += blockDim.x) Wp[idx] = sc[idx >> 7] * W[idx];
  for (int j = t; j < 128; j += blockDim.x) {
    float acc = 0;
    for (int k = 0; k < 128; k++) acc = fmaf(sh[k], W[k * 128 + j], acc);
    cb[j] = acc;
  }
}

// hw = y @ Wp + cb  -> bf16 out
__global__ __launch_bounds__(256) void k_gemm(const float* __restrict__ y,
                                              const float* __restrict__ Wp,
                                              const float* __restrict__ cb,
                                              unsigned short* __restrict__ hwb, int N_) {
  __shared__ float yl[64][128];
  int t = threadIdx.x;
  int base = blockIdx.x * 64;
  for (int i = t; i < 64 * 32; i += 256) {
    int r = i >> 5;
    int cq = (i & 31) * 4;
    int n = base + r;
    float4 v = (n < N_) ? *(const float4*)&y[n * 128 + cq] : float4{0, 0, 0, 0};
    *(float4*)&yl[r][cq] = v;
  }
  __syncthreads();
  int tn = t >> 5, tj = t & 31;
  float4 acc[8];
  float4 cbv = *(const float4*)&cb[tj * 4];
  #pragma unroll
  for (int r = 0; r < 8; r++) acc[r] = cbv;
  for (int kk = 0; kk < 128; kk++) {
    float4 w = *(const float4*)&Wp[kk * 128 + tj * 4];
    #pragma unroll
    for (int r = 0; r < 8; r++) {
      float yv = yl[tn * 8 + r][kk];
      acc[r].x = fmaf(yv, w.x, acc[r].x);
      acc[r].y = fmaf(yv, w.y, acc[r].y);
      acc[r].z = fmaf(yv, w.z, acc[r].z);
      acc[r].w = fmaf(yv, w.w, acc[r].w);
    }
  }
  #pragma unroll
  for (int r = 0; r < 8; r++) {
    int n = base + tn * 8 + r;
    if (n < N_) {
      uint2 o;
      o.x = bfpack(acc[r].x, acc[r].y);
      o.y = bfpack(acc[r].z, acc[r].w);
      *(uint2*)&hwb[n * 128 + tj * 4] = o;
    }
  }
}

// gather over bf16 hw; fused per-channel stats; optionally fused graph-pool (no y store)
template <int FUSE_POOL>
__global__ __launch_bounds__(256) void k_gatherb(const unsigned short* __restrict__ hwb,
                                                 const int* __restrict__ csr,
                                                 const int* __restrict__ row_ptr,
                                                 const float* __restrict__ dis,
                                                 const float* __restrict__ di,
                                                 const float* __restrict__ bL,
                                                 float* __restrict__ y,
                                                 float* __restrict__ S1, float* __restrict__ S2,
                                                 const int* __restrict__ batch,
                                                 float* __restrict__ pooled, int N_) {
  int lane = threadIdx.x & 63;
  int w = threadIdx.x >> 6;
  int wid = blockIdx.x * 4 + w;
  int nw = gridDim.x * 4;
  float s1x = 0, s1y = 0, s2x = 0, s2y = 0;
  float2 bb = *(const float2*)&bL[lane * 2];
  for (int n = wid; n < N_; n += nw) {
    int st = row_ptr[n], en = row_ptr[n + 1];
    float ax = 0.f, ay = 0.f;
    for (int e = st; e < en; e++) {
      int s_ = csr[e];
      float wc = dis[s_];
      unsigned int v = *(const unsigned int*)&hwb[s_ * 128 + lane * 2];
      ax = fmaf(wc, __uint_as_float(v << 16), ax);
      ay = fmaf(wc, __uint_as_float(v & 0xffff0000u), ay);
    }
    float dn = dis[n], dl = di[n];
    unsigned int hv = *(const unsigned int*)&hwb[n * 128 + lane * 2];
    float ox = fmaxf(fmaf(ax, dn, fmaf(__uint_as_float(hv << 16), dl, bb.x)), 0.f);
    float oy = fmaxf(fmaf(ay, dn, fmaf(__uint_as_float(hv & 0xffff0000u), dl, bb.y)), 0.f);
    s1x += ox; s1y += oy;
    s2x += ox * ox; s2y += oy * oy;
    if (FUSE_POOL) {
      int g = batch[n];
      atomicAdd(&pooled[g * 128 + lane * 2], ox);
      atomicAdd(&pooled[g * 128 + lane * 2 + 1], oy);
    } else {
      float2 o; o.x = ox; o.y = oy;
      *(float2*)&y[n * 128 + lane * 2] = o;
    }
  }
  // block-level stats reduction: rs[stat][wave][lane]
  __shared__ float rs[4][4][64];
  rs[0][w][lane] = s1x;
  rs[1][w][lane] = s1y;
  rs[2][w][lane] = s2x;
  rs[3][w][lane] = s2y;
  __syncthreads();
  float a = rs[w][0][lane] + rs[w][1][lane] + rs[w][2][lane] + rs[w][3][lane];
  if (w == 0) atomicAdd(&S1[lane * 2], a);
  else if (w == 1) atomicAdd(&S1[lane * 2 + 1], a);
  else if (w == 2) atomicAdd(&S2[lane * 2], a);
  else atomicAdd(&S2[lane * 2 + 1], a);
}

// fold BN3 into classifier
__global__ void k_prepC(const float* __restrict__ S1, const float* __restrict__ S2,
                        const float* __restrict__ g_, const float* __restrict__ b_,
                        const float* __restrict__ Wc1, const float* __restrict__ bc1,
                        float* __restrict__ Wc1p, float* __restrict__ bc1p, int N_) {
  __shared__ float sc[128], sh[128];
  int t = threadIdx.x;  // 128
  {
    float m = S1[t] / N_;
    float v = S2[t] / N_ - m * m;
    float s = g_[t] * rsqrtf(v + NEPS);
    sc[t] = s; sh[t] = b_[t] - m * s;
  }
  __syncthreads();
  for (int idx = t; idx < 128 * 64; idx += 128) Wc1p[idx] = sc[idx >> 6] * Wc1[idx];
  if (t < 64) {
    float acc = bc1[t];
    for (int k = 0; k < 128; k++) acc = fmaf(sh[k], Wc1[k * 64 + t], acc);
    bc1p[t] = acc;
  }
}

__device__ inline int lb_dev(const int* b, int n, int v) {
  int lo = 0, hi = n;
  while (lo < hi) { int mid = (lo + hi) >> 1; if (b[mid] < v) lo = mid + 1; else hi = mid; }
  return lo;
}

__global__ void k_cls(const float* __restrict__ pooled, const int* __restrict__ batch,
                      const float* __restrict__ Wc1p, const float* __restrict__ bc1p,
                      const float* __restrict__ Wc2, const float* __restrict__ bc2,
                      float* __restrict__ out, int N_, int G_) {
  __shared__ float p[128];
  __shared__ float z[64];
  __shared__ int s_lo, s_hi;
  int g = blockIdx.x, t = threadIdx.x;  // 64 threads
  if (t == 0) s_lo = lb_dev(batch, N_, g);
  if (t == 1) s_hi = lb_dev(batch, N_, g + 1);
  __syncthreads();
  float inv = 1.f / fmaxf((float)(s_hi - s_lo), 1.f);
  p[t] = pooled[g * 128 + t] * inv;
  p[t + 64] = pooled[g * 128 + 64 + t] * inv;
  __syncthreads();
  float acc = bc1p[t];
  for (int k = 0; k < 128; k++) acc = fmaf(p[k], Wc1p[k * 64 + t], acc);
  z[t] = fmaxf(acc, 0.f);
  __syncthreads();
  if (t < 2) {
    float o = bc2[t];
    for (int j = 0; j < 64; j++) o = fmaf(z[j], Wc2[j * 2 + t], o);
    out[g * 2 + t] = o;
  }
}

extern "C" void kernel_launch(void* const* d_in, const int* in_sizes, int n_in,
                              void* d_out, int out_size, void* d_ws, size_t ws_size,
                              hipStream_t stream) {
  const float* x    = (const float*)d_in[0];
  const int*   ei   = (const int*)d_in[1];
  const int*   batch= (const int*)d_in[2];
  const float* W1   = (const float*)d_in[3];
  const float* b1   = (const float*)d_in[4];
  const float* W2   = (const float*)d_in[5];
  const float* b2   = (const float*)d_in[6];
  const float* W3   = (const float*)d_in[7];
  const float* b3   = (const float*)d_in[8];
  const float* bn0g = (const float*)d_in[9];
  const float* bn0b = (const float*)d_in[10];
  const float* bn1g = (const float*)d_in[11];
  const float* bn1b = (const float*)d_in[12];
  const float* bn2g = (const float*)d_in[13];
  const float* bn2b = (const float*)d_in[14];
  const float* bn3g = (const float*)d_in[15];
  const float* bn3b = (const float*)d_in[16];
  const float* Wc1  = (const float*)d_in[17];
  const float* bc1  = (const float*)d_in[18];
  const float* Wc2  = (const float*)d_in[19];
  const float* bc2  = (const float*)d_in[20];

  const int N_ = in_sizes[2];
  const int E_ = in_sizes[1] / 2;
  const int G_ = out_size / 2;

  char* ws = (char*)d_ws;
  size_t off = 0;
  auto A = [&](size_t bytes) { size_t o = off; off = (off + bytes + 255) & ~(size_t)255; return o; };
  // zeroed region first
  size_t o_deg   = A((size_t)N_ * 4);
  size_t o_cur   = A((size_t)N_ * 4);
  size_t o_stats = A(1024 * 4);
  size_t o_pool  = A((size_t)G_ * 128 * 4);
  size_t zero_end = off;
  size_t o_rowp  = A((size_t)(N_ + 1) * 4);
  size_t o_bsum  = A(256 * 4);
  size_t o_csr   = A((size_t)E_ * 4);
  size_t o_dis   = A((size_t)N_ * 4);
  size_t o_di    = A((size_t)N_ * 4);
  size_t o_xp    = A((size_t)N_ * 16);
  size_t o_aggx  = A((size_t)N_ * 16);
  size_t o_W1a   = A(384 * 4);
  size_t o_u1    = A(128 * 4);
  size_t o_Wp    = A(16384 * 4);
  size_t o_cb    = A(128 * 4);
  size_t o_Wc1p  = A(8192 * 4);
  size_t o_bc1p  = A(64 * 4);
  size_t o_bufB  = A((size_t)N_ * 128 * 4);   // f32 activations
  size_t o_bufAh = A((size_t)N_ * 128 * 2);   // bf16 hw
  (void)ws_size; (void)n_in;

  int*   deg_cnt = (int*)(ws + o_deg);
  int*   cursor  = (int*)(ws + o_cur);
  float* stats   = (float*)(ws + o_stats);
  float* pooled  = (float*)(ws + o_pool);
  int*   row_ptr = (int*)(ws + o_rowp);
  int*   bsum    = (int*)(ws + o_bsum);
  int*   csr     = (int*)(ws + o_csr);
  float* dis     = (float*)(ws + o_dis);
  float* di      = (float*)(ws + o_di);
  float4* xp     = (float4*)(ws + o_xp);
  float4* aggx   = (float4*)(ws + o_aggx);
  float* W1a     = (float*)(ws + o_W1a);
  float* u1      = (float*)(ws + o_u1);
  float* Wp      = (float*)(ws + o_Wp);
  float* cb      = (float*)(ws + o_cb);
  float* Wc1p    = (float*)(ws + o_Wc1p);
  float* bc1p    = (float*)(ws + o_bc1p);
  float* bufB    = (float*)(ws + o_bufB);
  unsigned short* bufAh = (unsigned short*)(ws + o_bufAh);

  hipMemsetAsync(ws, 0, zero_end, stream);

  int nb_nodes = (N_ + 255) / 256;
  int nb_edges = 4096;

  k_deg<<<nb_edges, 256, 0, stream>>>(ei, deg_cnt, E_);
  k_xstats<<<256, 256, 0, stream>>>(x, stats, N_);
  k_scanA<<<nb_nodes, 256, 0, stream>>>(deg_cnt, row_ptr + 1, bsum, N_);
  k_scanB<<<1, 256, 0, stream>>>(bsum, nb_nodes);
  k_scanC<<<nb_nodes, 256, 0, stream>>>(row_ptr, bsum, deg_cnt, x, dis, di, xp, N_);
  k_scatter<<<nb_edges, 256, 0, stream>>>(ei, row_ptr, cursor, csr, E_);
  k_prep0<<<1, 128, 0, stream>>>(stats, bn0g, bn0b, W1, W1a, u1, N_);
  k_gather0<<<nb_nodes, 256, 0, stream>>>(xp, csr, row_ptr, di, aggx, N_);
  k_gemm1<<<(N_ * 32 + 255) / 256, 256, 0, stream>>>(aggx, W1a, u1, b1, bufB, N_);

  // layer 2
  k_stats<<<256, 128, 0, stream>>>(bufB, stats + 128, stats + 256, N_);
  k_prepW<<<1, 256, 0, stream>>>(stats + 128, stats + 256, bn1g, bn1b, W2, Wp, cb, N_);
  k_gemm<<<(N_ + 63) / 64, 256, 0, stream>>>(bufB, Wp, cb, bufAh, N_);
  k_gatherb<0><<<2048, 256, 0, stream>>>(bufAh, csr, row_ptr, dis, di, b2, bufB,
                                         stats + 384, stats + 512, batch, pooled, N_);

  // layer 3
  k_prepW<<<1, 256, 0, stream>>>(stats + 384, stats + 512, bn2g, bn2b, W3, Wp, cb, N_);
  k_gemm<<<(N_ + 63) / 64, 256, 0, stream>>>(bufB, Wp, cb, bufAh, N_);
  k_gatherb<1><<<2048, 256, 0, stream>>>(bufAh, csr, row_ptr, dis, di, b3, nullptr,
                                         stats + 640, stats + 768, batch, pooled, N_);

  // classifier (BN3 folded; pooled sums from atomics; counts via binary search)
  k_prepC<<<1, 128, 0, stream>>>(stats + 640, stats + 768, bn3g, bn3b, Wc1, bc1, Wc1p, bc1p, N_);
  k_cls<<<G_, 64, 0, stream>>>(pooled, batch, Wc1p, bc1p, Wc2, bc2, (float*)d_out, N_, G_);
}

// Round 3
// 558.005 us; speedup vs baseline: 1.7104x; 1.6540x over previous
//
#include <hip/hip_runtime.h>

#define NEPS 1e-5f

__device__ inline unsigned int bfpack(float a, float b) {
  unsigned int ua = __float_as_uint(a), ub = __float_as_uint(b);
  ua += 0x7fff + ((ua >> 16) & 1);
  ub += 0x7fff + ((ub >> 16) & 1);
  return (ua >> 16) | (ub & 0xffff0000u);
}
__device__ inline float bflo(unsigned int u) { return __uint_as_float(u << 16); }
__device__ inline float bfhi(unsigned int u) { return __uint_as_float(u & 0xffff0000u); }

// ---------------- CSR build ----------------
// degree count; atomic return value doubles as the CSR slot
__global__ void k_deg(const int* __restrict__ ei, int* __restrict__ deg_cnt,
                      int* __restrict__ slot, int E_) {
  int i = blockIdx.x * blockDim.x + threadIdx.x;
  int stride = gridDim.x * blockDim.x;
  for (int e = i; e < E_; e += stride) slot[e] = atomicAdd(&deg_cnt[ei[E_ + e]], 1);
}

__global__ __launch_bounds__(256) void k_scanA(const int* __restrict__ cnt, int* __restrict__ rp1,
                                               int* __restrict__ bsum, int N_) {
  int b = blockIdx.x, t = threadIdx.x;
  int i = b * 256 + t;
  int lane = t & 63, w = t >> 6;
  int sv = (i < N_) ? cnt[i] : 0;
  #pragma unroll
  for (int off = 1; off < 64; off <<= 1) {
    int u = __shfl_up(sv, off);
    if (lane >= off) sv += u;
  }
  __shared__ int wsum[4];
  if (lane == 63) wsum[w] = sv;
  __syncthreads();
  int add = 0;
  for (int k = 0; k < w; k++) add += wsum[k];
  sv += add;
  if (i < N_) rp1[i] = sv;
  if (t == 255) bsum[b] = sv;
}

__global__ __launch_bounds__(256) void k_scanB(int* __restrict__ bsum, int NB) {
  int t = threadIdx.x;
  int lane = t & 63, w = t >> 6;
  int sv = (t < NB) ? bsum[t] : 0;
  #pragma unroll
  for (int off = 1; off < 64; off <<= 1) {
    int u = __shfl_up(sv, off);
    if (lane >= off) sv += u;
  }
  __shared__ int wsum[4];
  if (lane == 63) wsum[w] = sv;
  __syncthreads();
  int add = 0;
  for (int k = 0; k < w; k++) add += wsum[k];
  sv += add;
  if (t < NB) bsum[t] = sv;
}

// add block offsets; compute dis; pack xp = {x0,x1,x2,dis}
__global__ __launch_bounds__(256) void k_scanC(int* __restrict__ row_ptr, const int* __restrict__ bsum,
                                               const int* __restrict__ deg_cnt, const float* __restrict__ x,
                                               float* __restrict__ dis, float4* __restrict__ xp, int N_) {
  int b = blockIdx.x;
  int i = b * 256 + threadIdx.x;
  if (i == 0) row_ptr[0] = 0;
  if (i >= N_) return;
  int base = b ? bsum[b - 1] : 0;
  row_ptr[i + 1] += base;
  float dg = (float)deg_cnt[i] + 1.0f;
  float ds_ = rsqrtf(dg);
  dis[i] = ds_;
  float4 v;
  v.x = x[i * 3 + 0]; v.y = x[i * 3 + 1]; v.z = x[i * 3 + 2]; v.w = ds_;
  xp[i] = v;
}

// atomic-free scatter using precomputed slots
__global__ void k_scatter(const int* __restrict__ ei, const int* __restrict__ row_ptr,
                          const int* __restrict__ slot, int* __restrict__ csr, int E_) {
  int i = blockIdx.x * blockDim.x + threadIdx.x;
  int stride = gridDim.x * blockDim.x;
  for (int e = i; e < E_; e += stride) {
    csr[row_ptr[ei[E_ + e]] + slot[e]] = ei[e];
  }
}

// ---------------- BN0 stats on x ----------------
__global__ void k_xstats(const float* __restrict__ x, float* __restrict__ stats, int N_) {
  float s1[3] = {0, 0, 0}, s2[3] = {0, 0, 0};
  int i = blockIdx.x * blockDim.x + threadIdx.x;
  int stride = gridDim.x * blockDim.x;
  for (int n = i; n < N_; n += stride) {
    #pragma unroll
    for (int c = 0; c < 3; c++) { float v = x[n * 3 + c]; s1[c] += v; s2[c] += v * v; }
  }
  #pragma unroll
  for (int c = 0; c < 3; c++) {
    for (int off = 32; off > 0; off >>= 1) {
      s1[c] += __shfl_down(s1[c], off);
      s2[c] += __shfl_down(s2[c], off);
    }
  }
  if ((threadIdx.x & 63) == 0) {
    #pragma unroll
    for (int c = 0; c < 3; c++) { atomicAdd(&stats[c], s1[c]); atomicAdd(&stats[4 + c], s2[c]); }
  }
}

// fold BN0 into W1
__global__ void k_prep0(const float* __restrict__ stats, const float* __restrict__ g0,
                        const float* __restrict__ b0, const float* __restrict__ W1,
                        float* __restrict__ W1a, float* __restrict__ u1, int N_) {
  __shared__ float a[3], dd[3];
  int t = threadIdx.x;
  if (t < 3) {
    float m = stats[t] / N_;
    float v = stats[4 + t] / N_ - m * m;
    float sc = g0[t] * rsqrtf(v + NEPS);
    a[t] = sc; dd[t] = b0[t] - m * sc;
  }
  __syncthreads();
  if (t < 128) {
    float u = 0.f;
    #pragma unroll
    for (int c = 0; c < 3; c++) {
      float w = W1[c * 128 + t];
      W1a[c * 128 + t] = a[c] * w;
      u = fmaf(dd[c], w, u);
    }
    u1[t] = u;
  }
}

// ---------------- fused layer 1: gather(x) + GEMM(3->128) + relu + stats ----------------
__global__ __launch_bounds__(256) void k_layer1(const float4* __restrict__ xp,
                                                const int* __restrict__ csr,
                                                const int* __restrict__ row_ptr,
                                                const float* __restrict__ W1a,
                                                const float* __restrict__ u1,
                                                const float* __restrict__ b1,
                                                float* __restrict__ y,
                                                float* __restrict__ S1, float* __restrict__ S2,
                                                int N_) {
  __shared__ float wl[5 * 128];
  int t = threadIdx.x;
  // wl rows: W1a[0..2], u1, b1
  for (int i = t; i < 384; i += 256) wl[i] = W1a[i];
  for (int i = t; i < 128; i += 256) { wl[384 + i] = u1[i]; wl[512 + i] = b1[i]; }
  __syncthreads();
  int lane = t & 63, w = t >> 6;
  int c0 = lane * 2;
  float2 w0 = *(const float2*)&wl[c0];
  float2 w1 = *(const float2*)&wl[128 + c0];
  float2 w2 = *(const float2*)&wl[256 + c0];
  float2 uu = *(const float2*)&wl[384 + c0];
  float2 bb = *(const float2*)&wl[512 + c0];
  int wid = blockIdx.x * 4 + w;
  int nw = gridDim.x * 4;
  float s1x = 0, s1y = 0, s2x = 0, s2y = 0;
  for (int n = wid; n < N_; n += nw) {
    int st = row_ptr[n], en = row_ptr[n + 1];
    float a0 = 0, a1 = 0, a2 = 0, sd = 0;
    for (int chunk = st; chunk < en; chunk += 64) {
      int cnt = min(64, en - chunk);
      if (lane < cnt) {
        float4 v = xp[csr[chunk + lane]];
        a0 = fmaf(v.w, v.x, a0);
        a1 = fmaf(v.w, v.y, a1);
        a2 = fmaf(v.w, v.z, a2);
        sd += v.w;
      }
    }
    #pragma unroll
    for (int m = 1; m < 64; m <<= 1) {
      a0 += __shfl_xor(a0, m);
      a1 += __shfl_xor(a1, m);
      a2 += __shfl_xor(a2, m);
      sd += __shfl_xor(sd, m);
    }
    float4 xn = xp[n];
    float dn = xn.w;
    // self as pseudo-edge with weight dn (dn*dn == 1/deg)
    a0 = fmaf(dn, xn.x, a0);
    a1 = fmaf(dn, xn.y, a1);
    a2 = fmaf(dn, xn.z, a2);
    sd += dn;
    float z0 = dn * a0, z1 = dn * a1, z2 = dn * a2, zw = dn * sd;
    float ox = fmaxf(fmaf(z0, w0.x, fmaf(z1, w1.x, fmaf(z2, w2.x, fmaf(zw, uu.x, bb.x)))), 0.f);
    float oy = fmaxf(fmaf(z0, w0.y, fmaf(z1, w1.y, fmaf(z2, w2.y, fmaf(zw, uu.y, bb.y)))), 0.f);
    s1x += ox; s1y += oy; s2x += ox * ox; s2y += oy * oy;
    float2 o; o.x = ox; o.y = oy;
    *(float2*)&y[(size_t)n * 128 + c0] = o;
  }
  __shared__ float rs[4][64][4];
  rs[w][lane][0] = s1x; rs[w][lane][1] = s1y;
  rs[w][lane][2] = s2x; rs[w][lane][3] = s2y;
  __syncthreads();
  int s = t >> 7, c = t & 127;
  int lsrc = c >> 1, sl = (s << 1) | (c & 1);
  float a = rs[0][lsrc][sl] + rs[1][lsrc][sl] + rs[2][lsrc][sl] + rs[3][lsrc][sl];
  atomicAdd(s ? &S2[c] : &S1[c], a);
}

// fold BN(prev) into W  (16 blocks)
__global__ __launch_bounds__(256) void k_prepW(const float* __restrict__ S1, const float* __restrict__ S2,
                                               const float* __restrict__ g_, const float* __restrict__ b_,
                                               const float* __restrict__ W, float* __restrict__ Wp,
                                               float* __restrict__ cb, int N_) {
  __shared__ float sc[128], sh[128];
  int t = threadIdx.x, b = blockIdx.x;
  if (t < 128) {
    float m = S1[t] / N_;
    float v = S2[t] / N_ - m * m;
    float s = g_[t] * rsqrtf(v + NEPS);
    sc[t] = s; sh[t] = b_[t] - m * s;
  }
  __syncthreads();
  for (int idx = b * 1024 + t; idx < (b + 1) * 1024; idx += 256) Wp[idx] = sc[idx >> 7] * W[idx];
  if (t < 8) {
    int j = b * 8 + t;
    float acc = 0;
    for (int k = 0; k < 128; k++) acc = fmaf(sh[k], W[k * 128 + j], acc);
    cb[j] = acc;
  }
}

// hw = y @ Wp + cb  -> bf16
__global__ __launch_bounds__(256) void k_gemm(const float* __restrict__ y,
                                              const float* __restrict__ Wp,
                                              const float* __restrict__ cb,
                                              unsigned short* __restrict__ hwb, int N_) {
  __shared__ float yl[64][128];
  int t = threadIdx.x;
  int base = blockIdx.x * 64;
  for (int i = t; i < 64 * 32; i += 256) {
    int r = i >> 5;
    int cq = (i & 31) * 4;
    int n = base + r;
    float4 v = (n < N_) ? *(const float4*)&y[(size_t)n * 128 + cq] : float4{0, 0, 0, 0};
    *(float4*)&yl[r][cq] = v;
  }
  __syncthreads();
  int tn = t >> 5, tj = t & 31;
  float4 acc[8];
  float4 cbv = *(const float4*)&cb[tj * 4];
  #pragma unroll
  for (int r = 0; r < 8; r++) acc[r] = cbv;
  for (int kk = 0; kk < 128; kk++) {
    float4 wv = *(const float4*)&Wp[kk * 128 + tj * 4];
    #pragma unroll
    for (int r = 0; r < 8; r++) {
      float yv = yl[tn * 8 + r][kk];
      acc[r].x = fmaf(yv, wv.x, acc[r].x);
      acc[r].y = fmaf(yv, wv.y, acc[r].y);
      acc[r].z = fmaf(yv, wv.z, acc[r].z);
      acc[r].w = fmaf(yv, wv.w, acc[r].w);
    }
  }
  #pragma unroll
  for (int r = 0; r < 8; r++) {
    int n = base + tn * 8 + r;
    if (n < N_) {
      uint2 o;
      o.x = bfpack(acc[r].x, acc[r].y);
      o.y = bfpack(acc[r].z, acc[r].w);
      *(uint2*)&hwb[(size_t)n * 128 + tj * 4] = o;
    }
  }
}

// MLP-friendly gather: 4 edges per memory instruction (4 x 16-lane groups),
// shfl-broadcast indices, butterfly combine; fused stats; optional fused pool.
template <int FUSE_POOL>
__global__ __launch_bounds__(256) void k_gatherb(const unsigned short* __restrict__ hwb,
                                                 const int* __restrict__ csr,
                                                 const int* __restrict__ row_ptr,
                                                 const float* __restrict__ dis,
                                                 const float* __restrict__ bL,
                                                 float* __restrict__ y,
                                                 float* __restrict__ S1, float* __restrict__ S2,
                                                 const int* __restrict__ batch,
                                                 float* __restrict__ pooled, int N_) {
  int t = threadIdx.x;
  int lane = t & 63, w = t >> 6;
  int g16 = lane >> 4, l16 = lane & 15;
  int c0 = l16 * 8 + g16 * 2;                  // this lane's 2 output channels
  float2 bb = *(const float2*)&bL[c0];
  const uint4* hw4 = (const uint4*)hwb;
  int wid = blockIdx.x * 4 + w;
  int nw = gridDim.x * 4;
  float s1a = 0, s1b = 0, s2a = 0, s2b = 0;
  for (int n = wid; n < N_; n += nw) {
    int st = row_ptr[n], en = row_ptr[n + 1];
    float acc[8] = {0, 0, 0, 0, 0, 0, 0, 0};
    for (int chunk = st; chunk < en; chunk += 64) {
      int cnt = min(64, en - chunk);
      int idx = (lane < cnt) ? csr[chunk + lane] : 0;
      float wgt = (lane < cnt) ? dis[idx] : 0.f;
      int nit = (cnt + 3) >> 2;
      #pragma unroll 4
      for (int i = 0; i < nit; i++) {
        int j = i * 4 + g16;
        int s_ = __shfl(idx, j);
        float wc = __shfl(wgt, j);
        uint4 v = hw4[(size_t)s_ * 16 + l16];
        acc[0] = fmaf(wc, bflo(v.x), acc[0]); acc[1] = fmaf(wc, bfhi(v.x), acc[1]);
        acc[2] = fmaf(wc, bflo(v.y), acc[2]); acc[3] = fmaf(wc, bfhi(v.y), acc[3]);
        acc[4] = fmaf(wc, bflo(v.z), acc[4]); acc[5] = fmaf(wc, bfhi(v.z), acc[5]);
        acc[6] = fmaf(wc, bflo(v.w), acc[6]); acc[7] = fmaf(wc, bfhi(v.w), acc[7]);
      }
    }
    float dn = dis[n];
    // self as pseudo-edge with weight dn (dn*dn == 1/deg); only group 0 adds it
    {
      uint4 v = hw4[(size_t)n * 16 + l16];
      float wc = (g16 == 0) ? dn : 0.f;
      acc[0] = fmaf(wc, bflo(v.x), acc[0]); acc[1] = fmaf(wc, bfhi(v.x), acc[1]);
      acc[2] = fmaf(wc, bflo(v.y), acc[2]); acc[3] = fmaf(wc, bfhi(v.y), acc[3]);
      acc[4] = fmaf(wc, bflo(v.z), acc[4]); acc[5] = fmaf(wc, bfhi(v.z), acc[5]);
      acc[6] = fmaf(wc, bflo(v.w), acc[6]); acc[7] = fmaf(wc, bfhi(v.w), acc[7]);
    }
    #pragma unroll
    for (int k = 0; k < 8; k++) {
      acc[k] += __shfl_xor(acc[k], 16);
      acc[k] += __shfl_xor(acc[k], 32);
    }
    // select this lane's 2 channels: acc[g16*2], acc[g16*2+1]
    float ta = (g16 & 1) ? acc[2] : acc[0];
    float tb = (g16 & 1) ? acc[6] : acc[4];
    float va = (g16 & 2) ? tb : ta;
    float tc = (g16 & 1) ? acc[3] : acc[1];
    float td = (g16 & 1) ? acc[7] : acc[5];
    float vb = (g16 & 2) ? td : tc;
    float ox = fmaxf(fmaf(va, dn, bb.x), 0.f);
    float oy = fmaxf(fmaf(vb, dn, bb.y), 0.f);
    s1a += ox; s1b += oy; s2a += ox * ox; s2b += oy * oy;
    if (FUSE_POOL) {
      int g = batch[n];
      atomicAdd(&pooled[g * 128 + c0], ox);
      atomicAdd(&pooled[g * 128 + c0 + 1], oy);
    } else {
      float2 o; o.x = ox; o.y = oy;
      *(float2*)&y[(size_t)n * 128 + c0] = o;
    }
  }
  __shared__ float rs[4][64][4];
  rs[w][lane][0] = s1a; rs[w][lane][1] = s1b;
  rs[w][lane][2] = s2a; rs[w][lane][3] = s2b;
  __syncthreads();
  int s = t >> 7, c = t & 127;
  int lsrc = (c >> 3) | (((c & 7) >> 1) << 4);
  int sl = (s << 1) | (c & 1);
  float a = rs[0][lsrc][sl] + rs[1][lsrc][sl] + rs[2][lsrc][sl] + rs[3][lsrc][sl];
  atomicAdd(s ? &S2[c] : &S1[c], a);
}

// fold BN3 into classifier
__global__ void k_prepC(const float* __restrict__ S1, const float* __restrict__ S2,
                        const float* __restrict__ g_, const float* __restrict__ b_,
                        const float* __restrict__ Wc1, const float* __restrict__ bc1,
                        float* __restrict__ Wc1p, float* __restrict__ bc1p, int N_) {
  __shared__ float sc[128], sh[128];
  int t = threadIdx.x;  // 128
  {
    float m = S1[t] / N_;
    float v = S2[t] / N_ - m * m;
    float s = g_[t] * rsqrtf(v + NEPS);
    sc[t] = s; sh[t] = b_[t] - m * s;
  }
  __syncthreads();
  for (int idx = t; idx < 128 * 64; idx += 128) Wc1p[idx] = sc[idx >> 6] * Wc1[idx];
  if (t < 64) {
    float acc = bc1[t];
    for (int k = 0; k < 128; k++) acc = fmaf(sh[k], Wc1[k * 64 + t], acc);
    bc1p[t] = acc;
  }
}

__device__ inline int lb_dev(const int* b, int n, int v) {
  int lo = 0, hi = n;
  while (lo < hi) { int mid = (lo + hi) >> 1; if (b[mid] < v) lo = mid + 1; else hi = mid; }
  return lo;
}

__global__ void k_cls(const float* __restrict__ pooled, const int* __restrict__ batch,
                      const float* __restrict__ Wc1p, const float* __restrict__ bc1p,
                      const float* __restrict__ Wc2, const float* __restrict__ bc2,
                      float* __restrict__ out, int N_, int G_) {
  __shared__ float p[128];
  __shared__ float z[64];
  __shared__ int s_lo, s_hi;
  int g = blockIdx.x, t = threadIdx.x;  // 64 threads
  if (t == 0) s_lo = lb_dev(batch, N_, g);
  if (t == 1) s_hi = lb_dev(batch, N_, g + 1);
  __syncthreads();
  float inv = 1.f / fmaxf((float)(s_hi - s_lo), 1.f);
  p[t] = pooled[g * 128 + t] * inv;
  p[t + 64] = pooled[g * 128 + 64 + t] * inv;
  __syncthreads();
  float acc = bc1p[t];
  for (int k = 0; k < 128; k++) acc = fmaf(p[k], Wc1p[k * 64 + t], acc);
  z[t] = fmaxf(acc, 0.f);
  __syncthreads();
  if (t < 2) {
    float o = bc2[t];
    for (int j = 0; j < 64; j++) o = fmaf(z[j], Wc2[j * 2 + t], o);
    out[g * 2 + t] = o;
  }
}

extern "C" void kernel_launch(void* const* d_in, const int* in_sizes, int n_in,
                              void* d_out, int out_size, void* d_ws, size_t ws_size,
                              hipStream_t stream) {
  const float* x    = (const float*)d_in[0];
  const int*   ei   = (const int*)d_in[1];
  const int*   batch= (const int*)d_in[2];
  const float* W1   = (const float*)d_in[3];
  const float* b1   = (const float*)d_in[4];
  const float* W2   = (const float*)d_in[5];
  const float* b2   = (const float*)d_in[6];
  const float* W3   = (const float*)d_in[7];
  const float* b3   = (const float*)d_in[8];
  const float* bn0g = (const float*)d_in[9];
  const float* bn0b = (const float*)d_in[10];
  const float* bn1g = (const float*)d_in[11];
  const float* bn1b = (const float*)d_in[12];
  const float* bn2g = (const float*)d_in[13];
  const float* bn2b = (const float*)d_in[14];
  const float* bn3g = (const float*)d_in[15];
  const float* bn3b = (const float*)d_in[16];
  const float* Wc1  = (const float*)d_in[17];
  const float* bc1  = (const float*)d_in[18];
  const float* Wc2  = (const float*)d_in[19];
  const float* bc2  = (const float*)d_in[20];

  const int N_ = in_sizes[2];
  const int E_ = in_sizes[1] / 2;
  const int G_ = out_size / 2;

  char* ws = (char*)d_ws;
  size_t off = 0;
  auto A = [&](size_t bytes) { size_t o = off; off = (off + bytes + 255) & ~(size_t)255; return o; };
  // zeroed region
  size_t o_deg   = A((size_t)N_ * 4);
  size_t o_stats = A(1024 * 4);
  size_t o_pool  = A((size_t)G_ * 128 * 4);
  size_t zero_end = off;
  size_t o_rowp  = A((size_t)(N_ + 1) * 4);
  size_t o_bsum  = A(256 * 4);
  size_t o_slot  = A((size_t)E_ * 4);
  size_t o_csr   = A((size_t)E_ * 4);
  size_t o_dis   = A((size_t)N_ * 4);
  size_t o_xp    = A((size_t)N_ * 16);
  size_t o_W1a   = A(384 * 4);
  size_t o_u1    = A(128 * 4);
  size_t o_Wp    = A(16384 * 4);
  size_t o_cb    = A(128 * 4);
  size_t o_Wc1p  = A(8192 * 4);
  size_t o_bc1p  = A(64 * 4);
  size_t o_bufB  = A((size_t)N_ * 128 * 4);   // f32 activations
  size_t o_bufAh = A((size_t)N_ * 128 * 2);   // bf16 hw
  (void)ws_size; (void)n_in;

  int*   deg_cnt = (int*)(ws + o_deg);
  float* stats   = (float*)(ws + o_stats);
  float* pooled  = (float*)(ws + o_pool);
  int*   row_ptr = (int*)(ws + o_rowp);
  int*   bsum    = (int*)(ws + o_bsum);
  int*   slot    = (int*)(ws + o_slot);
  int*   csr     = (int*)(ws + o_csr);
  float* dis     = (float*)(ws + o_dis);
  float4* xp     = (float4*)(ws + o_xp);
  float* W1a     = (float*)(ws + o_W1a);
  float* u1      = (float*)(ws + o_u1);
  float* Wp      = (float*)(ws + o_Wp);
  float* cb      = (float*)(ws + o_cb);
  float* Wc1p    = (float*)(ws + o_Wc1p);
  float* bc1p    = (float*)(ws + o_bc1p);
  float* bufB    = (float*)(ws + o_bufB);
  unsigned short* bufAh = (unsigned short*)(ws + o_bufAh);

  hipMemsetAsync(ws, 0, zero_end, stream);

  int nb_scan = (N_ + 255) / 256;

  k_deg<<<2048, 256, 0, stream>>>(ei, deg_cnt, slot, E_);
  k_xstats<<<256, 256, 0, stream>>>(x, stats, N_);
  k_scanA<<<nb_scan, 256, 0, stream>>>(deg_cnt, row_ptr + 1, bsum, N_);
  k_scanB<<<1, 256, 0, stream>>>(bsum, nb_scan);
  k_scanC<<<nb_scan, 256, 0, stream>>>(row_ptr, bsum, deg_cnt, x, dis, xp, N_);
  k_scatter<<<2048, 256, 0, stream>>>(ei, row_ptr, slot, csr, E_);
  k_prep0<<<1, 128, 0, stream>>>(stats, bn0g, bn0b, W1, W1a, u1, N_);

  // fused layer 1 (gather + 3->128 GEMM + relu + stats)
  k_layer1<<<2048, 256, 0, stream>>>(xp, csr, row_ptr, W1a, u1, b1, bufB,
                                     stats + 128, stats + 256, N_);

  // layer 2
  k_prepW<<<16, 256, 0, stream>>>(stats + 128, stats + 256, bn1g, bn1b, W2, Wp, cb, N_);
  k_gemm<<<(N_ + 63) / 64, 256, 0, stream>>>(bufB, Wp, cb, bufAh, N_);
  k_gatherb<0><<<2048, 256, 0, stream>>>(bufAh, csr, row_ptr, dis, b2, bufB,
                                         stats + 384, stats + 512, batch, pooled, N_);

  // layer 3
  k_prepW<<<16, 256, 0, stream>>>(stats + 384, stats + 512, bn2g, bn2b, W3, Wp, cb, N_);
  k_gemm<<<(N_ + 63) / 64, 256, 0, stream>>>(bufB, Wp, cb, bufAh, N_);
  k_gatherb<1><<<2048, 256, 0, stream>>>(bufAh, csr, row_ptr, dis, b3, nullptr,
                                         stats + 640, stats + 768, batch, pooled, N_);

  // classifier
  k_prepC<<<1, 128, 0, stream>>>(stats + 640, stats + 768, bn3g, bn3b, Wc1, bc1, Wc1p, bc1p, N_);
  k_cls<<<G_, 64, 0, stream>>>(pooled, batch, Wc1p, bc1p, Wc2, bc2, (float*)d_out, N_, G_);
}